// Round 2
// baseline (1245.844 us; speedup 1.0000x reference)
//
#include <hip/hip_runtime.h>
#include <math.h>

#define BB 16384
#define DD 1024
#define RR 64
#define EE 4
#define ER 256   // EE*RR

// K0: gates[b, 0..3] = softmax(x[b,:] @ gate_w.T). 64 rows/block, gate_w in LDS.
__global__ __launch_bounds__(256) void gates_kernel(const float* __restrict__ x,
                                                    const float* __restrict__ gate_w,
                                                    float* __restrict__ gates) {
    __shared__ float gw[EE * DD];  // 16 KB
    const int tid = threadIdx.x;
    #pragma unroll
    for (int p = 0; p < 4; ++p) {
        int f = (tid + p * 256) * 4;
        *(float4*)&gw[f] = *(const float4*)&gate_w[f];
    }
    __syncthreads();
    const int wave = tid >> 6, lane = tid & 63;
    int row_base = blockIdx.x * 64 + wave * 16;
    for (int rr = 0; rr < 16; ++rr) {
        int b = row_base + rr;
        const float* xr = &x[(size_t)b * DD];
        float p0 = 0.f, p1 = 0.f, p2 = 0.f, p3 = 0.f;
        #pragma unroll 4
        for (int k = 0; k < 16; ++k) {
            int d = lane + k * 64;           // coalesced 64-lane read
            float xv = xr[d];
            p0 += xv * gw[0 * DD + d];
            p1 += xv * gw[1 * DD + d];
            p2 += xv * gw[2 * DD + d];
            p3 += xv * gw[3 * DD + d];
        }
        #pragma unroll
        for (int off = 32; off > 0; off >>= 1) {
            p0 += __shfl_down(p0, off, 64);
            p1 += __shfl_down(p1, off, 64);
            p2 += __shfl_down(p2, off, 64);
            p3 += __shfl_down(p3, off, 64);
        }
        if (lane == 0) {
            float m = fmaxf(fmaxf(p0, p1), fmaxf(p2, p3));
            float e0 = __expf(p0 - m), e1 = __expf(p1 - m);
            float e2 = __expf(p2 - m), e3 = __expf(p3 - m);
            float inv = 1.f / (e0 + e1 + e2 + e3);
            float4 g = {e0 * inv, e1 * inv, e2 * inv, e3 * inv};
            *(float4*)&gates[(size_t)b * 4] = g;
        }
    }
}

// K1 (fused): t1 = tanh(x @ V_e)  [128x64 tile, full R range per block], then in-block:
// w[b, e*64+r] = gate[b,e] * tanh(sum_s C[e,r,s] * t1[b,s]). Writes gated w directly.
__global__ __launch_bounds__(256) void gemm1_fused(const float* __restrict__ x,
                                                   const float* __restrict__ Vl,
                                                   const float* __restrict__ Cl,
                                                   const float* __restrict__ gates,
                                                   float* __restrict__ w) {
    const int row0 = blockIdx.x * 128;
    const int e = blockIdx.y;
    __shared__ union {
        struct { float xs[128 * 36]; float vs[32 * 64]; } p1;               // 26.0 KB
        struct { float t1t[128 * 68]; float cs[64 * 65]; float gt[128]; } p2; // 51.9 KB
    } sm;
    const int tid = threadIdx.x;
    const int tx = tid & 15, ty = tid >> 4;
    float acc[8][4] = {};
    const float* Ve = Vl + (size_t)e * (DD * RR);
    for (int k0 = 0; k0 < DD; k0 += 32) {
        #pragma unroll
        for (int p = 0; p < 4; ++p) {            // xs: 128x32 = 1024 float4
            int f = tid + p * 256;
            int r = f >> 3;
            int c = (f & 7) * 4;
            float4 v = *(const float4*)&x[(size_t)(row0 + r) * DD + k0 + c];
            *(float4*)&sm.p1.xs[r * 36 + c] = v;
        }
        #pragma unroll
        for (int p = 0; p < 2; ++p) {            // vs: 32x64 = 512 float4
            int f = tid + p * 256;
            int r = f >> 4;
            int c = (f & 15) * 4;
            float4 v = *(const float4*)&Ve[(size_t)(k0 + r) * RR + c];
            *(float4*)&sm.p1.vs[r * 64 + c] = v;
        }
        __syncthreads();
        #pragma unroll
        for (int kk = 0; kk < 32; ++kk) {
            float4 bv = *(const float4*)&sm.p1.vs[kk * 64 + tx * 4];
            float bq[4] = {bv.x, bv.y, bv.z, bv.w};
            #pragma unroll
            for (int ii = 0; ii < 8; ++ii) {
                float a = sm.p1.xs[(ty + ii * 16) * 36 + kk];
                acc[ii][0] += a * bq[0];
                acc[ii][1] += a * bq[1];
                acc[ii][2] += a * bq[2];
                acc[ii][3] += a * bq[3];
            }
        }
        __syncthreads();
    }
    // ---- fused mix epilogue (xs/vs dead; reuse LDS as t1t/cs/gt) ----
    #pragma unroll
    for (int ii = 0; ii < 8; ++ii) {
        float4 o;
        o.x = tanhf(acc[ii][0]);
        o.y = tanhf(acc[ii][1]);
        o.z = tanhf(acc[ii][2]);
        o.w = tanhf(acc[ii][3]);
        *(float4*)&sm.p2.t1t[(ty + ii * 16) * 68 + tx * 4] = o;
    }
    #pragma unroll
    for (int p = 0; p < 4; ++p) {                // C[e]: 64x64 = 1024 float4
        int f = tid + p * 256;
        int r = f >> 4;
        int c = (f & 15) * 4;
        float4 v = *(const float4*)&Cl[(size_t)(e * RR + r) * RR + c];
        sm.p2.cs[r * 65 + c + 0] = v.x;
        sm.p2.cs[r * 65 + c + 1] = v.y;
        sm.p2.cs[r * 65 + c + 2] = v.z;
        sm.p2.cs[r * 65 + c + 3] = v.w;
    }
    if (tid < 128) sm.p2.gt[tid] = gates[(size_t)(row0 + tid) * 4 + e];
    __syncthreads();
    float acc2[8][4] = {};
    #pragma unroll 8
    for (int s = 0; s < RR; ++s) {
        float bq[4];
        bq[0] = sm.p2.cs[(tx * 4 + 0) * 65 + s];
        bq[1] = sm.p2.cs[(tx * 4 + 1) * 65 + s];
        bq[2] = sm.p2.cs[(tx * 4 + 2) * 65 + s];
        bq[3] = sm.p2.cs[(tx * 4 + 3) * 65 + s];
        #pragma unroll
        for (int ii = 0; ii < 8; ++ii) {
            float a = sm.p2.t1t[(ty + ii * 16) * 68 + s];
            acc2[ii][0] += a * bq[0];
            acc2[ii][1] += a * bq[1];
            acc2[ii][2] += a * bq[2];
            acc2[ii][3] += a * bq[3];
        }
    }
    #pragma unroll
    for (int ii = 0; ii < 8; ++ii) {
        int gb = row0 + ty + ii * 16;
        float g = sm.p2.gt[ty + ii * 16];
        float4 o;
        o.x = g * tanhf(acc2[ii][0]);
        o.y = g * tanhf(acc2[ii][1]);
        o.z = g * tanhf(acc2[ii][2]);
        o.w = g * tanhf(acc2[ii][3]);
        *(float4*)&w[(size_t)gb * ER + e * 64 + tx * 4] = o;
    }
}

// K3: out[b,d] = x0[b,d]*(sum_{e,r} w[b,e*64+r]*U[(e*DD+d)*RR+r] + bias[d]) + xl[b,d]
// 128x64 tile, 256 threads, micro 8x4, K=256 in 4 expert chunks. In-place safe (out may == xl).
__global__ __launch_bounds__(256) void gemm2_combine(const float* __restrict__ w,
                                                     const float* __restrict__ Ul,
                                                     const float* __restrict__ x0,
                                                     const float* xl,
                                                     const float* __restrict__ biasl,
                                                     float* out) {
    const int row0 = blockIdx.x * 128;
    const int d0 = blockIdx.y * 64;
    __shared__ float ws_[128 * 68];  // pad 68: aligned float4 writes, ty-groups 8 banks apart
    __shared__ float us[64 * 65];    // us[d][r]; pad 65 -> NT b-reads 2-way (free)
    const int tid = threadIdx.x;
    const int tx = tid & 15, ty = tid >> 4;
    float acc[8][4] = {};
    for (int e = 0; e < EE; ++e) {
        #pragma unroll
        for (int p = 0; p < 8; ++p) {            // w tile: 128x64 = 2048 float4
            int f = tid + p * 256;
            int r = f >> 4;
            int c = (f & 15) * 4;
            float4 v = *(const float4*)&w[(size_t)(row0 + r) * ER + e * 64 + c];
            *(float4*)&ws_[r * 68 + c] = v;
        }
        #pragma unroll
        for (int p = 0; p < 4; ++p) {            // U tile: us[d][r], 64x64
            int f = tid + p * 256;
            int dd = f >> 4;
            int c = (f & 15) * 4;
            float4 v = *(const float4*)&Ul[((size_t)e * DD + d0 + dd) * RR + c];
            us[dd * 65 + c + 0] = v.x;
            us[dd * 65 + c + 1] = v.y;
            us[dd * 65 + c + 2] = v.z;
            us[dd * 65 + c + 3] = v.w;
        }
        __syncthreads();
        #pragma unroll 8
        for (int kk = 0; kk < 64; ++kk) {
            float bq[4];
            bq[0] = us[(tx * 4 + 0) * 65 + kk];
            bq[1] = us[(tx * 4 + 1) * 65 + kk];
            bq[2] = us[(tx * 4 + 2) * 65 + kk];
            bq[3] = us[(tx * 4 + 3) * 65 + kk];
            #pragma unroll
            for (int ii = 0; ii < 8; ++ii) {
                float a = ws_[(ty + ii * 16) * 68 + kk];
                acc[ii][0] += a * bq[0];
                acc[ii][1] += a * bq[1];
                acc[ii][2] += a * bq[2];
                acc[ii][3] += a * bq[3];
            }
        }
        __syncthreads();
    }
    #pragma unroll
    for (int ii = 0; ii < 8; ++ii) {
        int gb = row0 + ty + ii * 16;
        size_t base = (size_t)gb * DD + d0 + tx * 4;
        float4 xv  = *(const float4*)&x0[base];
        float4 xlv = *(const float4*)&xl[base];
        float4 bv  = *(const float4*)&biasl[d0 + tx * 4];
        float4 o;
        o.x = xv.x * (acc[ii][0] + bv.x) + xlv.x;
        o.y = xv.y * (acc[ii][1] + bv.y) + xlv.y;
        o.z = xv.z * (acc[ii][2] + bv.z) + xlv.z;
        o.w = xv.w * (acc[ii][3] + bv.w) + xlv.w;
        *(float4*)&out[base] = o;
    }
}

extern "C" void kernel_launch(void* const* d_in, const int* in_sizes, int n_in,
                              void* d_out, int out_size, void* d_ws, size_t ws_size,
                              hipStream_t stream) {
    const float* inputs = (const float*)d_in[0];
    const float* U      = (const float*)d_in[1];
    const float* V      = (const float*)d_in[2];
    const float* C      = (const float*)d_in[3];
    const float* gw     = (const float*)d_in[4];
    const float* bias   = (const float*)d_in[5];
    float* out   = (float*)d_out;
    float* w     = (float*)d_ws;                       // B*ER floats (16.7 MB), gated w
    float* gates = w + (size_t)BB * ER;                // B*4 floats (256 KB)

    for (int i = 0; i < 3; ++i) {
        const float* x = (i == 0) ? inputs : out;      // d_out doubles as x_l buffer
        gates_kernel<<<dim3(BB / 64), 256, 0, stream>>>(x, gw, gates);
        gemm1_fused<<<dim3(BB / 128, EE), 256, 0, stream>>>(
            x, V + (size_t)i * EE * DD * RR, C + (size_t)i * EE * RR * RR, gates, w);
        gemm2_combine<<<dim3(BB / 128, DD / 64), 256, 0, stream>>>(
            w, U + (size_t)i * EE * DD * RR, inputs, x,
            bias + (size_t)i * DD, out);
    }
}

// Round 3
// 500.815 us; speedup vs baseline: 2.4876x; 2.4876x over previous
//
#include <hip/hip_runtime.h>
#include <math.h>

#define BB 16384
#define DD 1024
#define RR 64
#define EE 4
#define ER 256   // EE*RR
#define LL 3

#define LDA 56   // main-loop LDS stride (bf16 elems): 16B-aligned rows, b128 frag reads bank-uniform
#define LDT 88   // mix-phase LDS stride: same property for K=64 tiles

typedef __bf16 bf16x8 __attribute__((ext_vector_type(8)));
typedef float f32x4 __attribute__((ext_vector_type(4)));
typedef unsigned short us;

static __device__ inline us f2b(float f) {   // RNE f32->bf16
    union { float f; unsigned u; } c; c.f = f;
    return (us)((c.u + 0x7FFF + ((c.u >> 16) & 1)) >> 16);
}
static __device__ inline float fast_tanh(float x) {
    float t = __expf(2.f * x);               // +inf / 0 at extremes -> +-1 exactly
    return 1.f - 2.f / (t + 1.f);
}

// ---- one-time weight conversions (cover all 3 layers) ----
__global__ __launch_bounds__(256) void convU(const float* __restrict__ U, us* __restrict__ Ub) {
    int f = (blockIdx.x * 256 + threadIdx.x) * 4;      // LL*EE*DD*RR / 4 = 196608 threads
    float4 v = *(const float4*)&U[f];
    *(ushort4*)&Ub[f] = make_ushort4(f2b(v.x), f2b(v.y), f2b(v.z), f2b(v.w));
}

// V [le][d][r] f32  ->  Vt [le][r][d] bf16
__global__ __launch_bounds__(256) void convV(const float* __restrict__ V, us* __restrict__ Vt) {
    const int le = blockIdx.x;          // 0..11
    const int d0 = blockIdx.y * 64;
    __shared__ float t[64 * 65];
    const int tid = threadIdx.x;
    const float* Vb = V + (size_t)le * DD * RR;
    #pragma unroll
    for (int p = 0; p < 4; ++p) {
        int f = tid + p * 256; int dd = f >> 4; int c = (f & 15) * 4;
        float4 v = *(const float4*)&Vb[(size_t)(d0 + dd) * RR + c];
        t[dd * 65 + c + 0] = v.x; t[dd * 65 + c + 1] = v.y;
        t[dd * 65 + c + 2] = v.z; t[dd * 65 + c + 3] = v.w;
    }
    __syncthreads();
    int r = tid >> 2, dg = (tid & 3) * 16;
    us o[16];
    #pragma unroll
    for (int k = 0; k < 16; ++k) o[k] = f2b(t[(dg + k) * 65 + r]);
    us* dst = Vt + (size_t)le * RR * DD + (size_t)r * DD + d0 + dg;
    #pragma unroll
    for (int q = 0; q < 4; ++q) *(ushort4*)&dst[q * 4] = *(ushort4*)&o[q * 4];
}

// K0: gates[b,0..3] = softmax(x[b,:] @ gate_w.T)
__global__ __launch_bounds__(256) void gates_kernel(const float* __restrict__ x,
                                                    const float* __restrict__ gate_w,
                                                    float* __restrict__ gates) {
    __shared__ float gw[EE * DD];
    const int tid = threadIdx.x;
    #pragma unroll
    for (int p = 0; p < 4; ++p) {
        int f = (tid + p * 256) * 4;
        *(float4*)&gw[f] = *(const float4*)&gate_w[f];
    }
    __syncthreads();
    const int wave = tid >> 6, lane = tid & 63;
    int row_base = blockIdx.x * 64 + wave * 16;
    for (int rr = 0; rr < 16; ++rr) {
        int b = row_base + rr;
        const float* xr = &x[(size_t)b * DD];
        float p0 = 0.f, p1 = 0.f, p2 = 0.f, p3 = 0.f;
        #pragma unroll 4
        for (int k = 0; k < 16; ++k) {
            int d = lane + k * 64;
            float xv = xr[d];
            p0 += xv * gw[0 * DD + d]; p1 += xv * gw[1 * DD + d];
            p2 += xv * gw[2 * DD + d]; p3 += xv * gw[3 * DD + d];
        }
        #pragma unroll
        for (int off = 32; off > 0; off >>= 1) {
            p0 += __shfl_down(p0, off, 64); p1 += __shfl_down(p1, off, 64);
            p2 += __shfl_down(p2, off, 64); p3 += __shfl_down(p3, off, 64);
        }
        if (lane == 0) {
            float m = fmaxf(fmaxf(p0, p1), fmaxf(p2, p3));
            float e0 = __expf(p0 - m), e1 = __expf(p1 - m);
            float e2 = __expf(p2 - m), e3 = __expf(p3 - m);
            float inv = 1.f / (e0 + e1 + e2 + e3);
            *(float4*)&gates[(size_t)b * 4] = make_float4(e0 * inv, e1 * inv, e2 * inv, e3 * inv);
        }
    }
}

// K1 (MFMA, fused mix): w[b, e*64+r] = gate[b,e] * tanh( C_e @ tanh(x V_e) )
__global__ __launch_bounds__(256, 4) void gemm1_fused(const float* __restrict__ x,
                                                      const us* __restrict__ Vt,
                                                      const float* __restrict__ Cl,
                                                      const float* __restrict__ gates,
                                                      us* __restrict__ w) {
    const int row0 = blockIdx.x * 128;
    const int e = blockIdx.y;
    __shared__ union {
        struct { us As[128 * LDA]; us Bs[64 * LDA]; } m;                  // 21.5 KB
        struct { us Ts[128 * LDT]; us Cs[64 * LDT]; float gt[128]; } x2;  // 34.3 KB
    } sm;
    const int tid = threadIdx.x;
    const int lane = tid & 63, wave = tid >> 6;
    const int l15 = lane & 15, quad = lane >> 4;
    f32x4 acc[2][4] = {};
    const us* Ve = Vt + (size_t)e * RR * DD;
    for (int k0 = 0; k0 < DD; k0 += 32) {
        #pragma unroll
        for (int p = 0; p < 4; ++p) {          // A: x 128x32 f32 -> bf16
            int f = tid + p * 256; int r = f >> 3; int c = (f & 7) * 4;
            float4 v = *(const float4*)&x[(size_t)(row0 + r) * DD + k0 + c];
            *(ushort4*)&sm.m.As[r * LDA + c] = make_ushort4(f2b(v.x), f2b(v.y), f2b(v.z), f2b(v.w));
        }
        {                                       // B: Vt rows, 64 x 64B direct bf16 copy
            int r = tid >> 2; int c = (tid & 3) * 8;
            *(float4*)&sm.m.Bs[r * LDA + c] = *(const float4*)&Ve[(size_t)r * DD + k0 + c];
        }
        __syncthreads();
        bf16x8 a0 = *(const bf16x8*)&sm.m.As[(wave * 32 + l15) * LDA + quad * 8];
        bf16x8 a1 = *(const bf16x8*)&sm.m.As[(wave * 32 + 16 + l15) * LDA + quad * 8];
        #pragma unroll
        for (int nt = 0; nt < 4; ++nt) {
            bf16x8 b = *(const bf16x8*)&sm.m.Bs[(nt * 16 + l15) * LDA + quad * 8];
            acc[0][nt] = __builtin_amdgcn_mfma_f32_16x16x32_bf16(a0, b, acc[0][nt], 0, 0, 0);
            acc[1][nt] = __builtin_amdgcn_mfma_f32_16x16x32_bf16(a1, b, acc[1][nt], 0, 0, 0);
        }
        __syncthreads();
    }
    // ---- fused mix: t1 (C-layout) -> LDS bf16 (A-layout source), C_e staged bf16 ----
    #pragma unroll
    for (int mt = 0; mt < 2; ++mt)
        #pragma unroll
        for (int nt = 0; nt < 4; ++nt)
            #pragma unroll
            for (int i = 0; i < 4; ++i) {
                int row = wave * 32 + mt * 16 + quad * 4 + i;
                int col = nt * 16 + l15;
                sm.x2.Ts[row * LDT + col] = f2b(fast_tanh(acc[mt][nt][i]));
            }
    #pragma unroll
    for (int p = 0; p < 4; ++p) {              // C_e 64x64 f32 -> bf16
        int f = tid + p * 256; int r = f >> 4; int c = (f & 15) * 4;
        float4 v = *(const float4*)&Cl[(size_t)(e * RR + r) * RR + c];
        *(ushort4*)&sm.x2.Cs[r * LDT + c] = make_ushort4(f2b(v.x), f2b(v.y), f2b(v.z), f2b(v.w));
    }
    if (tid < 128) sm.x2.gt[tid] = gates[(size_t)(row0 + tid) * 4 + e];
    __syncthreads();
    f32x4 acc2[2][4] = {};
    #pragma unroll
    for (int k0 = 0; k0 < 64; k0 += 32) {
        bf16x8 a0 = *(const bf16x8*)&sm.x2.Ts[(wave * 32 + l15) * LDT + k0 + quad * 8];
        bf16x8 a1 = *(const bf16x8*)&sm.x2.Ts[(wave * 32 + 16 + l15) * LDT + k0 + quad * 8];
        #pragma unroll
        for (int nt = 0; nt < 4; ++nt) {
            bf16x8 b = *(const bf16x8*)&sm.x2.Cs[(nt * 16 + l15) * LDT + k0 + quad * 8];
            acc2[0][nt] = __builtin_amdgcn_mfma_f32_16x16x32_bf16(a0, b, acc2[0][nt], 0, 0, 0);
            acc2[1][nt] = __builtin_amdgcn_mfma_f32_16x16x32_bf16(a1, b, acc2[1][nt], 0, 0, 0);
        }
    }
    #pragma unroll
    for (int mt = 0; mt < 2; ++mt)
        #pragma unroll
        for (int nt = 0; nt < 4; ++nt)
            #pragma unroll
            for (int i = 0; i < 4; ++i) {
                int row = wave * 32 + mt * 16 + quad * 4 + i;
                int col = nt * 16 + l15;
                float g = sm.x2.gt[row];
                w[(size_t)(row0 + row) * ER + e * 64 + col] = f2b(g * fast_tanh(acc2[mt][nt][i]));
            }
}

// K2 (MFMA): out[b,d] = x0[b,d]*(w[b,:] @ Ueff[:,d] + bias[d]) + xl[b,d]
__global__ __launch_bounds__(256, 4) void gemm2_combine(const us* __restrict__ w,
                                                        const us* __restrict__ Ub,
                                                        const float* __restrict__ x0,
                                                        const float* xl,
                                                        const float* __restrict__ biasl,
                                                        float* out) {
    const int row0 = blockIdx.x * 128;
    const int d0 = blockIdx.y * 64;
    __shared__ us As[128 * LDA];
    __shared__ us Bs[64 * LDA];
    const int tid = threadIdx.x;
    const int lane = tid & 63, wave = tid >> 6;
    const int l15 = lane & 15, quad = lane >> 4;
    f32x4 acc[2][4] = {};
    for (int step = 0; step < 8; ++step) {
        int e = step >> 1;
        int kg = step * 32;
        #pragma unroll
        for (int p = 0; p < 2; ++p) {          // A: w 128x32 bf16 direct copy
            int f = tid + p * 256; int r = f >> 2; int c = (f & 3) * 8;
            *(float4*)&As[r * LDA + c] = *(const float4*)&w[(size_t)(row0 + r) * ER + kg + c];
        }
        {                                       // B: U[e][d0+dd][rh*32+..], native layout
            int dd = tid >> 2; int c = (tid & 3) * 8;
            *(float4*)&Bs[dd * LDA + c] =
                *(const float4*)&Ub[((size_t)e * DD + d0 + dd) * RR + (step & 1) * 32 + c];
        }
        __syncthreads();
        bf16x8 a0 = *(const bf16x8*)&As[(wave * 32 + l15) * LDA + quad * 8];
        bf16x8 a1 = *(const bf16x8*)&As[(wave * 32 + 16 + l15) * LDA + quad * 8];
        #pragma unroll
        for (int nt = 0; nt < 4; ++nt) {
            bf16x8 b = *(const bf16x8*)&Bs[(nt * 16 + l15) * LDA + quad * 8];
            acc[0][nt] = __builtin_amdgcn_mfma_f32_16x16x32_bf16(a0, b, acc[0][nt], 0, 0, 0);
            acc[1][nt] = __builtin_amdgcn_mfma_f32_16x16x32_bf16(a1, b, acc[1][nt], 0, 0, 0);
        }
        __syncthreads();
    }
    #pragma unroll
    for (int mt = 0; mt < 2; ++mt)
        #pragma unroll
        for (int nt = 0; nt < 4; ++nt) {
            int gd = d0 + nt * 16 + l15;
            float bv = biasl[gd];
            #pragma unroll
            for (int i = 0; i < 4; ++i) {
                int row = wave * 32 + mt * 16 + quad * 4 + i;
                size_t base = (size_t)(row0 + row) * DD + gd;
                out[base] = x0[base] * (acc[mt][nt][i] + bv) + xl[base];
            }
        }
}

extern "C" void kernel_launch(void* const* d_in, const int* in_sizes, int n_in,
                              void* d_out, int out_size, void* d_ws, size_t ws_size,
                              hipStream_t stream) {
    const float* inputs = (const float*)d_in[0];
    const float* U      = (const float*)d_in[1];
    const float* V      = (const float*)d_in[2];
    const float* C      = (const float*)d_in[3];
    const float* gw     = (const float*)d_in[4];
    const float* bias   = (const float*)d_in[5];
    float* out = (float*)d_out;

    // workspace: w bf16 (8.39 MB) | gates f32 (256 KB) | Vt bf16 (1.57 MB) | Ub bf16 (1.57 MB)
    us*    wbf   = (us*)d_ws;
    float* gates = (float*)(wbf + (size_t)BB * ER);
    us*    Vt    = (us*)(gates + (size_t)BB * 4);
    us*    Ub    = Vt + (size_t)LL * EE * RR * DD;

    convU<<<dim3(LL * EE * DD * RR / 1024), 256, 0, stream>>>(U, Ub);
    convV<<<dim3(LL * EE, DD / 64), 256, 0, stream>>>(V, Vt);

    for (int i = 0; i < LL; ++i) {
        const float* x = (i == 0) ? inputs : out;   // d_out doubles as x_l buffer
        gates_kernel<<<dim3(BB / 64), 256, 0, stream>>>(x, gw, gates);
        gemm1_fused<<<dim3(BB / 128, EE), 256, 0, stream>>>(
            x, Vt + (size_t)i * EE * RR * DD, C + (size_t)i * EE * RR * RR, gates, wbf);
        gemm2_combine<<<dim3(BB / 128, DD / 64), 256, 0, stream>>>(
            wbf, Ub + (size_t)i * EE * DD * RR, inputs, x, bias + (size_t)i * DD, out);
    }
}

// Round 4
// 469.023 us; speedup vs baseline: 2.6563x; 1.0678x over previous
//
#include <hip/hip_runtime.h>
#include <math.h>

#define BB 16384
#define DD 1024
#define RR 64
#define EE 4
#define ER 256   // EE*RR
#define LL 3

#define LDK 40   // main-loop LDS stride (bf16 elems): 16B-aligned, gcd(20,32)=4 -> 8 start banks (<=2-way, free)
#define LDM 72   // mix-phase stride for 64-wide panels: same property

typedef __bf16 bf16x8 __attribute__((ext_vector_type(8)));
typedef float f32x4 __attribute__((ext_vector_type(4)));
typedef unsigned short us;

static __device__ inline us f2b(float f) {   // RNE f32->bf16
    union { float f; unsigned u; } c; c.f = f;
    return (us)((c.u + 0x7FFF + ((c.u >> 16) & 1)) >> 16);
}
static __device__ inline float b2f(us v) {
    union { unsigned u; float f; } c; c.u = ((unsigned)v) << 16;
    return c.f;
}
static __device__ inline float fast_tanh(float x) {
    float t = __expf(2.f * x);               // inf/0 at extremes -> +-1 exactly
    return 1.f - 2.f / (t + 1.f);
}

// ---- one-time conversions ----
__global__ __launch_bounds__(256) void convX(const float* __restrict__ x, us* __restrict__ xb) {
    int f = (blockIdx.x * 256 + threadIdx.x) * 4;
    float4 v = *(const float4*)&x[f];
    *(ushort4*)&xb[f] = make_ushort4(f2b(v.x), f2b(v.y), f2b(v.z), f2b(v.w));
}
__global__ __launch_bounds__(256) void convU(const float* __restrict__ U, us* __restrict__ Ub) {
    int f = (blockIdx.x * 256 + threadIdx.x) * 4;
    float4 v = *(const float4*)&U[f];
    *(ushort4*)&Ub[f] = make_ushort4(f2b(v.x), f2b(v.y), f2b(v.z), f2b(v.w));
}
// V [le][d][r] f32 -> Vt [le][r][d] bf16
__global__ __launch_bounds__(256) void convV(const float* __restrict__ V, us* __restrict__ Vt) {
    const int le = blockIdx.x;
    const int d0 = blockIdx.y * 64;
    __shared__ float t[64 * 65];
    const int tid = threadIdx.x;
    const float* Vb = V + (size_t)le * DD * RR;
    #pragma unroll
    for (int p = 0; p < 4; ++p) {
        int f = tid + p * 256; int dd = f >> 4; int c = (f & 15) * 4;
        float4 v = *(const float4*)&Vb[(size_t)(d0 + dd) * RR + c];
        t[dd * 65 + c + 0] = v.x; t[dd * 65 + c + 1] = v.y;
        t[dd * 65 + c + 2] = v.z; t[dd * 65 + c + 3] = v.w;
    }
    __syncthreads();
    int r = tid >> 2, dg = (tid & 3) * 16;
    us o[16];
    #pragma unroll
    for (int k = 0; k < 16; ++k) o[k] = f2b(t[(dg + k) * 65 + r]);
    us* dst = Vt + (size_t)le * RR * DD + (size_t)r * DD + d0 + dg;
    #pragma unroll
    for (int q = 0; q < 4; ++q) *(ushort4*)&dst[q * 4] = *(ushort4*)&o[q * 4];
}

// K0: gates[b,0..3] = softmax(x[b,:] @ gate_w.T), x read as bf16 shadow
__global__ __launch_bounds__(256) void gates_kernel(const us* __restrict__ xb,
                                                    const float* __restrict__ gate_w,
                                                    float* __restrict__ gates) {
    __shared__ float gw[EE * DD];
    const int tid = threadIdx.x;
    #pragma unroll
    for (int p = 0; p < 4; ++p) {
        int f = (tid + p * 256) * 4;
        *(float4*)&gw[f] = *(const float4*)&gate_w[f];
    }
    __syncthreads();
    const int wave = tid >> 6, lane = tid & 63;
    int row_base = blockIdx.x * 64 + wave * 16;
    for (int rr = 0; rr < 16; ++rr) {
        int b = row_base + rr;
        const us* xr = &xb[(size_t)b * DD];
        float p0 = 0.f, p1 = 0.f, p2 = 0.f, p3 = 0.f;
        #pragma unroll 4
        for (int k = 0; k < 16; ++k) {
            int d = lane + k * 64;
            float xv = b2f(xr[d]);
            p0 += xv * gw[0 * DD + d]; p1 += xv * gw[1 * DD + d];
            p2 += xv * gw[2 * DD + d]; p3 += xv * gw[3 * DD + d];
        }
        #pragma unroll
        for (int off = 32; off > 0; off >>= 1) {
            p0 += __shfl_down(p0, off, 64); p1 += __shfl_down(p1, off, 64);
            p2 += __shfl_down(p2, off, 64); p3 += __shfl_down(p3, off, 64);
        }
        if (lane == 0) {
            float m = fmaxf(fmaxf(p0, p1), fmaxf(p2, p3));
            float e0 = __expf(p0 - m), e1 = __expf(p1 - m);
            float e2 = __expf(p2 - m), e3 = __expf(p3 - m);
            float inv = 1.f / (e0 + e1 + e2 + e3);
            *(float4*)&gates[(size_t)b * 4] = make_float4(e0 * inv, e1 * inv, e2 * inv, e3 * inv);
        }
    }
}

// K1 (swapped operands): D[r][b] = Vt_e . x^T ; then w[b][e*64+r'] = g*tanh(C_e @ tanh(D))
// 128 threads (2 waves); block tile: 64 r x 128 b; per wave acc[4 mt(r)][4 nt(b)]
__global__ __launch_bounds__(128) void gemm1_fused(const us* __restrict__ xb,
                                                   const us* __restrict__ Vt,
                                                   const float* __restrict__ Cl,
                                                   const float* __restrict__ gates,
                                                   us* __restrict__ w) {
    const int row0 = blockIdx.x * 128;     // b
    const int e = blockIdx.y;
    __shared__ union {
        struct { us Av[64 * LDK]; us Bx[128 * LDK]; } m;                 // 15.4 KB
        struct { us Tt[128 * LDM]; us Cs[64 * LDM]; float gt[128]; } x2; // 28.2 KB
    } sm;
    const int tid = threadIdx.x;
    const int lane = tid & 63, wave = tid >> 6;
    const int l15 = lane & 15, quad = lane >> 4;
    f32x4 acc[4][4] = {};
    const us* Ve = Vt + (size_t)e * RR * DD;
    for (int k0 = 0; k0 < DD; k0 += 32) {
        #pragma unroll
        for (int p = 0; p < 2; ++p) {      // Av: 64 r x 32 k, direct bf16 16B copies
            int f = tid + p * 128; int r = f >> 2; int c = (f & 3) * 8;
            *(float4*)&sm.m.Av[r * LDK + c] = *(const float4*)&Ve[(size_t)r * DD + k0 + c];
        }
        #pragma unroll
        for (int p = 0; p < 4; ++p) {      // Bx: 128 b x 32 k
            int f = tid + p * 128; int r = f >> 2; int c = (f & 3) * 8;
            *(float4*)&sm.m.Bx[r * LDK + c] = *(const float4*)&xb[(size_t)(row0 + r) * DD + k0 + c];
        }
        __syncthreads();
        bf16x8 af[4], bfr[4];
        #pragma unroll
        for (int mt = 0; mt < 4; ++mt) af[mt] = *(const bf16x8*)&sm.m.Av[(mt * 16 + l15) * LDK + quad * 8];
        #pragma unroll
        for (int nt = 0; nt < 4; ++nt) bfr[nt] = *(const bf16x8*)&sm.m.Bx[(wave * 64 + nt * 16 + l15) * LDK + quad * 8];
        #pragma unroll
        for (int mt = 0; mt < 4; ++mt)
            #pragma unroll
            for (int nt = 0; nt < 4; ++nt)
                acc[mt][nt] = __builtin_amdgcn_mfma_f32_16x16x32_bf16(af[mt], bfr[nt], acc[mt][nt], 0, 0, 0);
        __syncthreads();
    }
    // ---- mix: t1 D[r][b] -> Tt[b][r] bf16 via ushort4 (thread holds 4 consecutive r) ----
    #pragma unroll
    for (int mt = 0; mt < 4; ++mt)
        #pragma unroll
        for (int nt = 0; nt < 4; ++nt) {
            int b = wave * 64 + nt * 16 + l15;
            int r = mt * 16 + quad * 4;
            us o[4];
            #pragma unroll
            for (int i = 0; i < 4; ++i) o[i] = f2b(fast_tanh(acc[mt][nt][i]));
            *(ushort4*)&sm.x2.Tt[b * LDM + r] = *(ushort4*)o;
        }
    #pragma unroll
    for (int p = 0; p < 4; ++p) {          // Cs: C_e 64x64 f32 -> bf16
        int f = tid + p * 128; int r = f >> 3; int c = (f & 7) * 8;
        float4 v0 = *(const float4*)&Cl[(size_t)(e * RR + r) * RR + c];
        float4 v1 = *(const float4*)&Cl[(size_t)(e * RR + r) * RR + c + 4];
        *(ushort4*)&sm.x2.Cs[r * LDM + c]     = make_ushort4(f2b(v0.x), f2b(v0.y), f2b(v0.z), f2b(v0.w));
        *(ushort4*)&sm.x2.Cs[r * LDM + c + 4] = make_ushort4(f2b(v1.x), f2b(v1.y), f2b(v1.z), f2b(v1.w));
    }
    sm.x2.gt[tid] = gates[(size_t)(row0 + tid) * 4 + e];
    __syncthreads();
    f32x4 acc2[4][4] = {};
    #pragma unroll
    for (int ks = 0; ks < 2; ++ks) {
        bf16x8 af[4], bfr[4];
        #pragma unroll
        for (int mt = 0; mt < 4; ++mt) af[mt] = *(const bf16x8*)&sm.x2.Cs[(mt * 16 + l15) * LDM + ks * 32 + quad * 8];
        #pragma unroll
        for (int nt = 0; nt < 4; ++nt) bfr[nt] = *(const bf16x8*)&sm.x2.Tt[(wave * 64 + nt * 16 + l15) * LDM + ks * 32 + quad * 8];
        #pragma unroll
        for (int mt = 0; mt < 4; ++mt)
            #pragma unroll
            for (int nt = 0; nt < 4; ++nt)
                acc2[mt][nt] = __builtin_amdgcn_mfma_f32_16x16x32_bf16(af[mt], bfr[nt], acc2[mt][nt], 0, 0, 0);
    }
    #pragma unroll
    for (int mt = 0; mt < 4; ++mt)
        #pragma unroll
        for (int nt = 0; nt < 4; ++nt) {
            int b = wave * 64 + nt * 16 + l15;
            int r = mt * 16 + quad * 4;
            float g = sm.x2.gt[b];
            us o[4];
            #pragma unroll
            for (int i = 0; i < 4; ++i) o[i] = f2b(g * fast_tanh(acc2[mt][nt][i]));
            *(ushort4*)&w[(size_t)(row0 + b) * ER + e * 64 + r] = *(ushort4*)o;
        }
}

// K2 (swapped): D[d][b] = U . w^T ; out[b][d] = x0*(D+bias)+xl, also writes xb=bf16(out)
// 128 threads; block tile 64 d x 128 b; K=256 in 8 steps
__global__ __launch_bounds__(128) void gemm2_combine(const us* __restrict__ w,
                                                     const us* __restrict__ Ub,
                                                     const float* __restrict__ x0,
                                                     const float* xl,
                                                     const float* __restrict__ biasl,
                                                     float* out, us* __restrict__ xbo) {
    const int row0 = blockIdx.x * 128;     // b
    const int d0 = blockIdx.y * 64;        // d
    __shared__ us Au[64 * LDK];
    __shared__ us Bw[128 * LDK];
    const int tid = threadIdx.x;
    const int lane = tid & 63, wave = tid >> 6;
    const int l15 = lane & 15, quad = lane >> 4;
    f32x4 acc[4][4] = {};
    for (int step = 0; step < 8; ++step) {
        int e = step >> 1, r0 = (step & 1) * 32;
        #pragma unroll
        for (int p = 0; p < 2; ++p) {      // Au: 64 d x 32 r
            int f = tid + p * 128; int dd = f >> 2; int c = (f & 3) * 8;
            *(float4*)&Au[dd * LDK + c] = *(const float4*)&Ub[((size_t)e * DD + d0 + dd) * RR + r0 + c];
        }
        #pragma unroll
        for (int p = 0; p < 4; ++p) {      // Bw: 128 b x 32 r
            int f = tid + p * 128; int r = f >> 2; int c = (f & 3) * 8;
            *(float4*)&Bw[r * LDK + c] = *(const float4*)&w[(size_t)(row0 + r) * ER + e * 64 + r0 + c];
        }
        __syncthreads();
        bf16x8 af[4], bfr[4];
        #pragma unroll
        for (int mt = 0; mt < 4; ++mt) af[mt] = *(const bf16x8*)&Au[(mt * 16 + l15) * LDK + quad * 8];
        #pragma unroll
        for (int nt = 0; nt < 4; ++nt) bfr[nt] = *(const bf16x8*)&Bw[(wave * 64 + nt * 16 + l15) * LDK + quad * 8];
        #pragma unroll
        for (int mt = 0; mt < 4; ++mt)
            #pragma unroll
            for (int nt = 0; nt < 4; ++nt)
                acc[mt][nt] = __builtin_amdgcn_mfma_f32_16x16x32_bf16(af[mt], bfr[nt], acc[mt][nt], 0, 0, 0);
        __syncthreads();
    }
    // epilogue: thread holds 4 consecutive d per (mt,nt) -> float4 everywhere
    #pragma unroll
    for (int nt = 0; nt < 4; ++nt) {
        int b = row0 + wave * 64 + nt * 16 + l15;
        #pragma unroll
        for (int mt = 0; mt < 4; ++mt) {
            int d = d0 + mt * 16 + quad * 4;
            size_t base = (size_t)b * DD + d;
            float4 xv  = *(const float4*)&x0[base];
            float4 xlv = *(const float4*)&xl[base];
            float4 bv  = *(const float4*)&biasl[d];
            float4 o;
            o.x = xv.x * (acc[mt][nt][0] + bv.x) + xlv.x;
            o.y = xv.y * (acc[mt][nt][1] + bv.y) + xlv.y;
            o.z = xv.z * (acc[mt][nt][2] + bv.z) + xlv.z;
            o.w = xv.w * (acc[mt][nt][3] + bv.w) + xlv.w;
            *(float4*)&out[base] = o;
            *(ushort4*)&xbo[base] = make_ushort4(f2b(o.x), f2b(o.y), f2b(o.z), f2b(o.w));
        }
    }
}

extern "C" void kernel_launch(void* const* d_in, const int* in_sizes, int n_in,
                              void* d_out, int out_size, void* d_ws, size_t ws_size,
                              hipStream_t stream) {
    const float* inputs = (const float*)d_in[0];
    const float* U      = (const float*)d_in[1];
    const float* V      = (const float*)d_in[2];
    const float* C      = (const float*)d_in[3];
    const float* gw     = (const float*)d_in[4];
    const float* bias   = (const float*)d_in[5];
    float* out = (float*)d_out;

    // ws layout: xb bf16 (33.55 MB) | w bf16 (8.39 MB) | gates f32 (256 KB) | Vt (1.57 MB) | Ub (1.57 MB)
    us*    xb    = (us*)d_ws;
    us*    wbf   = xb + (size_t)BB * DD;
    float* gates = (float*)(wbf + (size_t)BB * ER);
    us*    Vt    = (us*)(gates + (size_t)BB * 4);
    us*    Ub    = Vt + (size_t)LL * EE * RR * DD;

    convX<<<dim3(BB * DD / 1024), 256, 0, stream>>>(inputs, xb);
    convU<<<dim3(LL * EE * DD * RR / 1024), 256, 0, stream>>>(U, Ub);
    convV<<<dim3(LL * EE, DD / 64), 256, 0, stream>>>(V, Vt);

    for (int i = 0; i < LL; ++i) {
        const float* x = (i == 0) ? inputs : out;   // f32 x_l (residual stream)
        gates_kernel<<<dim3(BB / 64), 256, 0, stream>>>(xb, gw, gates);
        gemm1_fused<<<dim3(BB / 128, EE), 128, 0, stream>>>(
            xb, Vt + (size_t)i * EE * RR * DD, C + (size_t)i * EE * RR * RR, gates, wbf);
        gemm2_combine<<<dim3(BB / 128, DD / 64), 128, 0, stream>>>(
            wbf, Ub + (size_t)i * EE * DD * RR, inputs, x, bias + (size_t)i * DD, out, xb);
    }
}

// Round 5
// 447.854 us; speedup vs baseline: 2.7818x; 1.0473x over previous
//
#include <hip/hip_runtime.h>
#include <math.h>

#define BB 16384
#define DD 1024
#define RR 64
#define EE 4
#define ER 256   // EE*RR
#define LL 3

#define LDK 40   // main-loop LDS stride (bf16): 16B-aligned, 8 start banks -> <=2-way (free)
#define LDM 72   // mix-phase Tt stride

typedef __bf16 bf16x8 __attribute__((ext_vector_type(8)));
typedef float f32x4 __attribute__((ext_vector_type(4)));
typedef unsigned short us;

static __device__ inline us f2b(float f) {   // RNE f32->bf16
    union { float f; unsigned u; } c; c.f = f;
    return (us)((c.u + 0x7FFF + ((c.u >> 16) & 1)) >> 16);
}
static __device__ inline float b2f(us v) {
    union { unsigned u; float f; } c; c.u = ((unsigned)v) << 16;
    return c.f;
}
static __device__ inline float fast_tanh(float x) {
    float t = __expf(2.f * x);               // inf/0 at extremes -> +-1 exactly
    return 1.f - 2.f / (t + 1.f);
}

// generic f32 -> bf16 (4 elems/thread)
__global__ __launch_bounds__(256) void convF2B(const float* __restrict__ s, us* __restrict__ d) {
    int f = (blockIdx.x * 256 + threadIdx.x) * 4;
    float4 v = *(const float4*)&s[f];
    *(ushort4*)&d[f] = make_ushort4(f2b(v.x), f2b(v.y), f2b(v.z), f2b(v.w));
}
// V [le][d][r] f32 -> Vt [le][r][d] bf16
__global__ __launch_bounds__(256) void convV(const float* __restrict__ V, us* __restrict__ Vt) {
    const int le = blockIdx.x;
    const int d0 = blockIdx.y * 64;
    __shared__ float t[64 * 65];
    const int tid = threadIdx.x;
    const float* Vb = V + (size_t)le * DD * RR;
    #pragma unroll
    for (int p = 0; p < 4; ++p) {
        int f = tid + p * 256; int dd = f >> 4; int c = (f & 15) * 4;
        float4 v = *(const float4*)&Vb[(size_t)(d0 + dd) * RR + c];
        t[dd * 65 + c + 0] = v.x; t[dd * 65 + c + 1] = v.y;
        t[dd * 65 + c + 2] = v.z; t[dd * 65 + c + 3] = v.w;
    }
    __syncthreads();
    int r = tid >> 2, dg = (tid & 3) * 16;
    us o[16];
    #pragma unroll
    for (int k = 0; k < 16; ++k) o[k] = f2b(t[(dg + k) * 65 + r]);
    us* dst = Vt + (size_t)le * RR * DD + (size_t)r * DD + d0 + dg;
    #pragma unroll
    for (int q = 0; q < 4; ++q) *(ushort4*)&dst[q * 4] = *(ushort4*)&o[q * 4];
}

// K0: gates[b,0..3] = softmax(x[b,:] @ gate_w.T), x read as bf16 shadow
__global__ __launch_bounds__(256) void gates_kernel(const us* __restrict__ xb,
                                                    const float* __restrict__ gate_w,
                                                    float* __restrict__ gates) {
    __shared__ float gw[EE * DD];
    const int tid = threadIdx.x;
    #pragma unroll
    for (int p = 0; p < 4; ++p) {
        int f = (tid + p * 256) * 4;
        *(float4*)&gw[f] = *(const float4*)&gate_w[f];
    }
    __syncthreads();
    const int wave = tid >> 6, lane = tid & 63;
    int row_base = blockIdx.x * 64 + wave * 16;
    for (int rr = 0; rr < 16; ++rr) {
        int b = row_base + rr;
        const us* xr = &xb[(size_t)b * DD];
        float p0 = 0.f, p1 = 0.f, p2 = 0.f, p3 = 0.f;
        #pragma unroll 4
        for (int k = 0; k < 16; ++k) {
            int d = lane + k * 64;
            float xv = b2f(xr[d]);
            p0 += xv * gw[0 * DD + d]; p1 += xv * gw[1 * DD + d];
            p2 += xv * gw[2 * DD + d]; p3 += xv * gw[3 * DD + d];
        }
        #pragma unroll
        for (int off = 32; off > 0; off >>= 1) {
            p0 += __shfl_down(p0, off, 64); p1 += __shfl_down(p1, off, 64);
            p2 += __shfl_down(p2, off, 64); p3 += __shfl_down(p3, off, 64);
        }
        if (lane == 0) {
            float m = fmaxf(fmaxf(p0, p1), fmaxf(p2, p3));
            float e0 = __expf(p0 - m), e1 = __expf(p1 - m);
            float e2 = __expf(p2 - m), e3 = __expf(p3 - m);
            float inv = 1.f / (e0 + e1 + e2 + e3);
            *(float4*)&gates[(size_t)b * 4] = make_float4(e0 * inv, e1 * inv, e2 * inv, e3 * inv);
        }
    }
}

// K1: D[r][b] = Vt_e . xb^T ; w[b][e*64+r'] = g*tanh(C_e @ tanh(D))
// 128 threads (2 waves, wave = b-half); C-frags loaded direct from global bf16 Cb
__global__ __launch_bounds__(128) void gemm1_fused(const us* __restrict__ xb,
                                                   const us* __restrict__ Vt,
                                                   const us* __restrict__ Ce,
                                                   const float* __restrict__ gates,
                                                   us* __restrict__ w) {
    const int row0 = blockIdx.x * 128;     // b
    const int e = blockIdx.y;
    __shared__ union {
        struct { us Av[64 * LDK]; us Bx[128 * LDK]; } m;   // 15.4 KB
        struct { us Tt[128 * LDM]; float gt[128]; } x2;    // 18.9 KB
    } sm;
    const int tid = threadIdx.x;
    const int lane = tid & 63, wave = tid >> 6;
    const int l15 = lane & 15, quad = lane >> 4;
    f32x4 acc[4][4] = {};
    const us* Ve = Vt + (size_t)e * RR * DD;
    const us* Cb = Ce + (size_t)e * RR * RR;
    for (int k0 = 0; k0 < DD; k0 += 32) {
        #pragma unroll
        for (int p = 0; p < 2; ++p) {      // Av: 64 r x 32 k
            int f = tid + p * 128; int r = f >> 2; int c = (f & 3) * 8;
            *(float4*)&sm.m.Av[r * LDK + c] = *(const float4*)&Ve[(size_t)r * DD + k0 + c];
        }
        #pragma unroll
        for (int p = 0; p < 4; ++p) {      // Bx: 128 b x 32 k
            int f = tid + p * 128; int r = f >> 2; int c = (f & 3) * 8;
            *(float4*)&sm.m.Bx[r * LDK + c] = *(const float4*)&xb[(size_t)(row0 + r) * DD + k0 + c];
        }
        __syncthreads();
        bf16x8 af[4], bfr[4];
        #pragma unroll
        for (int mt = 0; mt < 4; ++mt) af[mt] = *(const bf16x8*)&sm.m.Av[(mt * 16 + l15) * LDK + quad * 8];
        #pragma unroll
        for (int nt = 0; nt < 4; ++nt) bfr[nt] = *(const bf16x8*)&sm.m.Bx[(wave * 64 + nt * 16 + l15) * LDK + quad * 8];
        #pragma unroll
        for (int mt = 0; mt < 4; ++mt)
            #pragma unroll
            for (int nt = 0; nt < 4; ++nt)
                acc[mt][nt] = __builtin_amdgcn_mfma_f32_16x16x32_bf16(af[mt], bfr[nt], acc[mt][nt], 0, 0, 0);
        __syncthreads();
    }
    // ---- mix: t1 D[r][b] -> Tt[b][r] bf16 (thread holds 4 consecutive r) ----
    #pragma unroll
    for (int mt = 0; mt < 4; ++mt)
        #pragma unroll
        for (int nt = 0; nt < 4; ++nt) {
            int b = wave * 64 + nt * 16 + l15;
            int r = mt * 16 + quad * 4;
            us o[4];
            #pragma unroll
            for (int i = 0; i < 4; ++i) o[i] = f2b(fast_tanh(acc[mt][nt][i]));
            *(ushort4*)&sm.x2.Tt[b * LDM + r] = *(ushort4*)o;
        }
    sm.x2.gt[tid] = gates[(size_t)(row0 + tid) * 4 + e];
    __syncthreads();
    f32x4 acc2[4][4] = {};
    #pragma unroll
    for (int ks = 0; ks < 2; ++ks) {
        bf16x8 af[4], bfr[4];
        #pragma unroll
        for (int mt = 0; mt < 4; ++mt)   // C_e[r'][s] direct from global (L2-hot, 16B/thread)
            af[mt] = *(const bf16x8*)&Cb[(size_t)(mt * 16 + l15) * RR + ks * 32 + quad * 8];
        #pragma unroll
        for (int nt = 0; nt < 4; ++nt)
            bfr[nt] = *(const bf16x8*)&sm.x2.Tt[(wave * 64 + nt * 16 + l15) * LDM + ks * 32 + quad * 8];
        #pragma unroll
        for (int mt = 0; mt < 4; ++mt)
            #pragma unroll
            for (int nt = 0; nt < 4; ++nt)
                acc2[mt][nt] = __builtin_amdgcn_mfma_f32_16x16x32_bf16(af[mt], bfr[nt], acc2[mt][nt], 0, 0, 0);
    }
    #pragma unroll
    for (int mt = 0; mt < 4; ++mt)
        #pragma unroll
        for (int nt = 0; nt < 4; ++nt) {
            int b = wave * 64 + nt * 16 + l15;
            int r = mt * 16 + quad * 4;
            float g = sm.x2.gt[b];
            us o[4];
            #pragma unroll
            for (int i = 0; i < 4; ++i) o[i] = f2b(g * fast_tanh(acc2[mt][nt][i]));
            *(ushort4*)&w[(size_t)(row0 + b) * ER + e * 64 + r] = *(ushort4*)o;
        }
}

// K2: D[d][b] = U . w^T ; res = x0*(D+bias) + xl(bf16).  Layers 0-1: write xb only (bf16
// residual stream); last layer: write f32 out only. 256 thr, tile 128d x 128b, wave=(dh,bh).
__global__ __launch_bounds__(256) void gemm2_combine(const us* __restrict__ w,
                                                     const us* __restrict__ Ub,
                                                     const float* __restrict__ x0,
                                                     us* __restrict__ xb,
                                                     const float* __restrict__ biasl,
                                                     float* __restrict__ out, int last) {
    const int row0 = blockIdx.x * 128;     // b
    const int d0 = blockIdx.y * 128;       // d
    __shared__ us Au[128 * LDK];
    __shared__ us Bw[128 * LDK];
    const int tid = threadIdx.x;
    const int lane = tid & 63, wave = tid >> 6;
    const int bh = wave & 1, dh = wave >> 1;
    const int l15 = lane & 15, quad = lane >> 4;
    f32x4 acc[4][4] = {};
    for (int step = 0; step < 8; ++step) {
        int e = step >> 1, r0 = (step & 1) * 32;
        #pragma unroll
        for (int p = 0; p < 2; ++p) {      // Au: 128 d x 32 r
            int f = tid + p * 256; int r = f >> 2; int c = (f & 3) * 8;
            *(float4*)&Au[r * LDK + c] = *(const float4*)&Ub[((size_t)e * DD + d0 + r) * RR + r0 + c];
        }
        #pragma unroll
        for (int p = 0; p < 2; ++p) {      // Bw: 128 b x 32 r
            int f = tid + p * 256; int r = f >> 2; int c = (f & 3) * 8;
            *(float4*)&Bw[r * LDK + c] = *(const float4*)&w[(size_t)(row0 + r) * ER + e * 64 + r0 + c];
        }
        __syncthreads();
        bf16x8 af[4], bfr[4];
        #pragma unroll
        for (int mt = 0; mt < 4; ++mt) af[mt] = *(const bf16x8*)&Au[(dh * 64 + mt * 16 + l15) * LDK + quad * 8];
        #pragma unroll
        for (int nt = 0; nt < 4; ++nt) bfr[nt] = *(const bf16x8*)&Bw[(bh * 64 + nt * 16 + l15) * LDK + quad * 8];
        #pragma unroll
        for (int mt = 0; mt < 4; ++mt)
            #pragma unroll
            for (int nt = 0; nt < 4; ++nt)
                acc[mt][nt] = __builtin_amdgcn_mfma_f32_16x16x32_bf16(af[mt], bfr[nt], acc[mt][nt], 0, 0, 0);
        __syncthreads();
    }
    #pragma unroll
    for (int nt = 0; nt < 4; ++nt) {
        int b = row0 + bh * 64 + nt * 16 + l15;
        #pragma unroll
        for (int mt = 0; mt < 4; ++mt) {
            int d = d0 + dh * 64 + mt * 16 + quad * 4;
            size_t base = (size_t)b * DD + d;
            float4 xv = *(const float4*)&x0[base];
            ushort4 xlb = *(const ushort4*)&xb[base];
            float4 bv = *(const float4*)&biasl[d];
            float4 o;
            o.x = xv.x * (acc[mt][nt][0] + bv.x) + b2f(xlb.x);
            o.y = xv.y * (acc[mt][nt][1] + bv.y) + b2f(xlb.y);
            o.z = xv.z * (acc[mt][nt][2] + bv.z) + b2f(xlb.z);
            o.w = xv.w * (acc[mt][nt][3] + bv.w) + b2f(xlb.w);
            if (last) {
                *(float4*)&out[base] = o;
            } else {
                *(ushort4*)&xb[base] = make_ushort4(f2b(o.x), f2b(o.y), f2b(o.z), f2b(o.w));
            }
        }
    }
}

extern "C" void kernel_launch(void* const* d_in, const int* in_sizes, int n_in,
                              void* d_out, int out_size, void* d_ws, size_t ws_size,
                              hipStream_t stream) {
    const float* inputs = (const float*)d_in[0];
    const float* U      = (const float*)d_in[1];
    const float* V      = (const float*)d_in[2];
    const float* C      = (const float*)d_in[3];
    const float* gw     = (const float*)d_in[4];
    const float* bias   = (const float*)d_in[5];
    float* out = (float*)d_out;

    // ws: xb 33.55 MB | w 8.39 | gates 0.26 | Vt 1.57 | Ub 1.57 | Cb 0.10  = ~45.5 MB
    us*    xb    = (us*)d_ws;
    us*    wbf   = xb + (size_t)BB * DD;
    float* gates = (float*)(wbf + (size_t)BB * ER);
    us*    Vt    = (us*)(gates + (size_t)BB * 4);
    us*    Ub    = Vt + (size_t)LL * EE * RR * DD;
    us*    Cb    = Ub + (size_t)LL * EE * DD * RR;

    convF2B<<<dim3(BB * DD / 1024), 256, 0, stream>>>(inputs, xb);
    convF2B<<<dim3(LL * EE * DD * RR / 1024), 256, 0, stream>>>(U, Ub);
    convF2B<<<dim3(LL * EE * RR * RR / 1024), 256, 0, stream>>>(C, Cb);
    convV<<<dim3(LL * EE, DD / 64), 256, 0, stream>>>(V, Vt);

    for (int i = 0; i < LL; ++i) {
        gates_kernel<<<dim3(BB / 64), 256, 0, stream>>>(xb, gw, gates);
        gemm1_fused<<<dim3(BB / 128, EE), 128, 0, stream>>>(
            xb, Vt + (size_t)i * EE * RR * DD, Cb + (size_t)i * EE * RR * RR, gates, wbf);
        gemm2_combine<<<dim3(BB / 128, DD / 128), 256, 0, stream>>>(
            wbf, Ub + (size_t)i * EE * DD * RR, inputs, xb, bias + (size_t)i * DD,
            out, i == LL - 1);
    }
}